// Round 1
// baseline (119.636 us; speedup 1.0000x reference)
//
#include <hip/hip_runtime.h>
#include <hip/hip_bf16.h>

#define N 8192
#define D 192
#define NCHUNK 16
#define COLS_PER_CHUNK (N / NCHUNK)   // 512
#define ROWS_PER_WAVE 32

typedef short short8 __attribute__((ext_vector_type(8)));
typedef float f32x4 __attribute__((ext_vector_type(4)));

// ---------------- Kernel 1: row-normalize + diagonal dot (fp32) ----------------
// One wave (64 lanes) per sample n. pos = x[n,0,:], anc = x[n,1,:], D=192 -> 3 elems/lane.
__global__ __launch_bounds__(256) void norm_kernel(
    const float* __restrict__ x,
    __hip_bfloat16* __restrict__ posn,
    __hip_bfloat16* __restrict__ ancn,
    float* __restrict__ diag) {
  int gw = (int)((blockIdx.x * 256 + threadIdx.x) >> 6);
  int lane = threadIdx.x & 63;
  if (gw >= N) return;
  const float* row = x + (size_t)gw * (2 * D);
  float p[3], a[3];
  float ssp = 0.f, ssa = 0.f, dt = 0.f;
#pragma unroll
  for (int j = 0; j < 3; ++j) {
    p[j] = row[lane + 64 * j];
    a[j] = row[D + lane + 64 * j];
    ssp += p[j] * p[j];
    ssa += a[j] * a[j];
    dt += p[j] * a[j];
  }
#pragma unroll
  for (int off = 32; off >= 1; off >>= 1) {
    ssp += __shfl_xor(ssp, off, 64);
    ssa += __shfl_xor(ssa, off, 64);
    dt += __shfl_xor(dt, off, 64);
  }
  float invp = 1.f / fmaxf(sqrtf(ssp), 1e-8f);
  float inva = 1.f / fmaxf(sqrtf(ssa), 1e-8f);
#pragma unroll
  for (int j = 0; j < 3; ++j) {
    posn[(size_t)gw * D + lane + 64 * j] = __float2bfloat16(p[j] * invp);
    ancn[(size_t)gw * D + lane + 64 * j] = __float2bfloat16(a[j] * inva);
  }
  if (lane == 0) diag[gw] = dt * invp * inva;
}

// ---------------- Kernel 2: GEMM (pos_n x anc_n^T) + fused partial sum-exp ----------------
// Each wave owns 32 rows (A fragments fully in registers: 2 rowsets x 6 ksteps).
// Block = 4 waves = 128 consecutive rows, all waves share one 512-col chunk (L1 reuse of B).
// Fixed softmax max M = |w|+b (|dot|<=1 for unit vectors), so sum-exp needs no running max.
__global__ __launch_bounds__(256, 4) void gemm_lse_kernel(
    const __hip_bfloat16* __restrict__ posn,
    const __hip_bfloat16* __restrict__ ancn,
    const float* __restrict__ wp,
    const float* __restrict__ bp,
    float* __restrict__ partial) {
  const int lane = (int)(threadIdx.x & 63);
  const int wv = (int)(threadIdx.x >> 6);
  const int chunk = (int)(blockIdx.x & (NCHUNK - 1));
  const int rt = (int)(blockIdx.x >> 4) * 4 + wv;  // row-tile 0..255
  const int rowBase = rt * ROWS_PER_WAVE;
  const int colBase = chunk * COLS_PER_CHUNK;

  const float w = *wp;
  const float LOG2E = 1.4426950408889634f;
  const float c1 = w * LOG2E;
  const float c0 = -fabsf(w) * LOG2E;  // (b - M)*log2e with M = |w|+b

  const int r15 = lane & 15;
  const int khi = (lane >> 4) * 8;

  // A fragments: 2 rowsets x 6 ksteps, each lane holds 8 bf16 (16B contiguous)
  short8 af[2][6];
#pragma unroll
  for (int rs = 0; rs < 2; ++rs)
#pragma unroll
    for (int ks = 0; ks < 6; ++ks)
      af[rs][ks] = *(const short8*)(posn + (size_t)(rowBase + rs * 16 + r15) * D + khi + ks * 32);

  float s0[4] = {0.f, 0.f, 0.f, 0.f};
  float s1[4] = {0.f, 0.f, 0.f, 0.f};

  for (int g = 0; g < COLS_PER_CHUNK / 16; ++g) {
    const __hip_bfloat16* bptr = ancn + (size_t)(colBase + g * 16 + r15) * D + khi;
    f32x4 acc0 = {0.f, 0.f, 0.f, 0.f};
    f32x4 acc1 = {0.f, 0.f, 0.f, 0.f};
#pragma unroll
    for (int ks = 0; ks < 6; ++ks) {
      short8 bf = *(const short8*)(bptr + ks * 32);
      acc0 = __builtin_amdgcn_mfma_f32_16x16x32_bf16(af[0][ks], bf, acc0, 0, 0, 0);
      acc1 = __builtin_amdgcn_mfma_f32_16x16x32_bf16(af[1][ks], bf, acc1, 0, 0, 0);
    }
#pragma unroll
    for (int r = 0; r < 4; ++r) {
      s0[r] += exp2f(fmaf(acc0[r], c1, c0));
      s1[r] += exp2f(fmaf(acc1[r], c1, c0));
    }
  }

  // Reduce over the 16 lanes of each group (these hold the 16 cols of the C tile)
#pragma unroll
  for (int off = 1; off < 16; off <<= 1) {
#pragma unroll
    for (int r = 0; r < 4; ++r) {
      s0[r] += __shfl_xor(s0[r], off, 64);
      s1[r] += __shfl_xor(s1[r], off, 64);
    }
  }

  if (r15 == 0) {
    const int rgrp = (lane >> 4) * 4;  // C rows: (lane>>4)*4 + reg
#pragma unroll
    for (int r = 0; r < 4; ++r) {
      partial[(size_t)chunk * N + rowBase + rgrp + r] = s0[r];
      partial[(size_t)chunk * N + rowBase + 16 + rgrp + r] = s1[r];
    }
  }
}

// ---------------- Kernel 3: combine partials, LSE, mean, write loss ----------------
__global__ __launch_bounds__(256) void finalize_kernel(
    const float* __restrict__ partial,
    const float* __restrict__ diag,
    const float* __restrict__ wp,
    const float* __restrict__ bp,
    float* __restrict__ out) {
  const float w = *wp, b = *bp;
  const float M = fabsf(w) + b;
  float acc = 0.f;
  for (int i = (int)threadIdx.x; i < N; i += 256) {
    float s = 0.f;
#pragma unroll
    for (int c = 0; c < NCHUNK; ++c) s += partial[(size_t)c * N + i];
    float lse = M + logf(s);
    acc += fmaf(diag[i], w, b) - lse;
  }
#pragma unroll
  for (int off = 32; off >= 1; off >>= 1) acc += __shfl_xor(acc, off, 64);
  __shared__ float red[4];
  if ((threadIdx.x & 63) == 0) red[threadIdx.x >> 6] = acc;
  __syncthreads();
  if (threadIdx.x == 0) {
    float t = red[0] + red[1] + red[2] + red[3];
    out[0] = -t / (float)N;
  }
}

extern "C" void kernel_launch(void* const* d_in, const int* in_sizes, int n_in,
                              void* d_out, int out_size, void* d_ws, size_t ws_size,
                              hipStream_t stream) {
  const float* x = (const float*)d_in[0];
  const float* wp = (const float*)d_in[1];
  const float* bp = (const float*)d_in[2];
  float* out = (float*)d_out;

  char* ws = (char*)d_ws;
  __hip_bfloat16* posn = (__hip_bfloat16*)ws;                    // 8192*192*2 = 3,145,728 B
  __hip_bfloat16* ancn = (__hip_bfloat16*)(ws + 3145728);        // 3,145,728 B
  float* diag = (float*)(ws + 6291456);                          // 32,768 B
  float* partial = (float*)(ws + 6324224);                       // 16*8192*4 = 524,288 B

  norm_kernel<<<N / 4, 256, 0, stream>>>(x, posn, ancn, diag);
  gemm_lse_kernel<<<(N / ROWS_PER_WAVE / 4) * NCHUNK, 256, 0, stream>>>(posn, ancn, wp, bp, partial);
  finalize_kernel<<<1, 256, 0, stream>>>(partial, diag, wp, bp, out);
}

// Round 2
// 58.060 us; speedup vs baseline: 2.0605x; 2.0605x over previous
//
#include <hip/hip_runtime.h>
#include <hip/hip_bf16.h>

#define N 8192
#define D 192
#define NCHUNK 16
#define CHUNK_COLS 512
#define TILE_COLS 64
#define NTILES (CHUNK_COLS / TILE_COLS)   // 8
#define BLOCK_ROWS 256                    // 4 waves x 64 rows
#define FRAG_BYTES 1024                   // one MFMA B fragment: 64 lanes x 16B
#define TILE_BYTES ((TILE_COLS / 16) * 6 * FRAG_BYTES)  // 4 coltiles x 6 ksteps = 24576 B

typedef short short8 __attribute__((ext_vector_type(8)));
typedef float f32x4 __attribute__((ext_vector_type(4)));

#define GLOAD16(gptr, lptr)                                                              \
  __builtin_amdgcn_global_load_lds((const __attribute__((address_space(1))) void*)(gptr), \
                                   (__attribute__((address_space(3))) void*)(lptr), 16, 0, 0)

// ---------------- Kernel 1: row-normalize + diagonal dot (fp32) ----------------
__global__ __launch_bounds__(256) void norm_kernel(
    const float* __restrict__ x,
    __hip_bfloat16* __restrict__ posn,
    __hip_bfloat16* __restrict__ ancn,
    float* __restrict__ diag) {
  int gw = (int)((blockIdx.x * 256 + threadIdx.x) >> 6);
  int lane = threadIdx.x & 63;
  if (gw >= N) return;
  const float* row = x + (size_t)gw * (2 * D);
  float p[3], a[3];
  float ssp = 0.f, ssa = 0.f, dt = 0.f;
#pragma unroll
  for (int j = 0; j < 3; ++j) {
    p[j] = row[lane + 64 * j];
    a[j] = row[D + lane + 64 * j];
    ssp += p[j] * p[j];
    ssa += a[j] * a[j];
    dt += p[j] * a[j];
  }
#pragma unroll
  for (int off = 32; off >= 1; off >>= 1) {
    ssp += __shfl_xor(ssp, off, 64);
    ssa += __shfl_xor(ssa, off, 64);
    dt += __shfl_xor(dt, off, 64);
  }
  float invp = 1.f / fmaxf(sqrtf(ssp), 1e-8f);
  float inva = 1.f / fmaxf(sqrtf(ssa), 1e-8f);
#pragma unroll
  for (int j = 0; j < 3; ++j) {
    posn[(size_t)gw * D + lane + 64 * j] = __float2bfloat16(p[j] * invp);
    ancn[(size_t)gw * D + lane + 64 * j] = __float2bfloat16(a[j] * inva);
  }
  if (lane == 0) diag[gw] = dt * invp * inva;
}

// ---------------- Kernel 2: tiled GEMM + fused partial sum-exp ----------------
// Block = 4 waves, each owning 64 rows (4 rowsets). A fragments live in registers.
// B staged per 64-col tile into LDS in MFMA-fragment order via global_load_lds
// (pre-swizzled global gather -> linear LDS -> conflict-free ds_read_b128),
// double-buffered. Fixed softmax max M=|w|+b (unit vectors => |dot|<=1).
__global__ __launch_bounds__(256, 2) void gemm_lse_kernel(
    const __hip_bfloat16* __restrict__ posn,
    const __hip_bfloat16* __restrict__ ancn,
    const float* __restrict__ wp,
    const float* __restrict__ bp,
    float* __restrict__ partial) {
  __shared__ char lds[2 * TILE_BYTES];

  const int lane = (int)(threadIdx.x & 63);
  const int wv = (int)(threadIdx.x >> 6);
  const int chunk = (int)(blockIdx.x & (NCHUNK - 1));
  const int rb = (int)(blockIdx.x >> 4);
  const int rowBase = rb * BLOCK_ROWS + wv * 64;
  const int colBase = chunk * CHUNK_COLS;

  const float w = *wp;
  const float LOG2E = 1.4426950408889634f;
  const float c1 = w * LOG2E;
  const float c0 = -fabsf(w) * LOG2E;  // (b - M)*log2e, M = |w|+b

  const int r15 = lane & 15;
  const int khi = (lane >> 4) * 8;

  // A fragments: 4 rowsets x 6 ksteps, 16B/lane each
  short8 af[4][6];
#pragma unroll
  for (int rs = 0; rs < 4; ++rs)
#pragma unroll
    for (int ks = 0; ks < 6; ++ks)
      af[rs][ks] = *(const short8*)(posn + (size_t)(rowBase + rs * 16 + r15) * D + ks * 32 + khi);

  // stage tile t into buffer buf: wave wv handles coltile ct==wv (16 cols x 192 k)
  auto stage = [&](int buf, int t) {
    const __hip_bfloat16* g =
        ancn + (size_t)(colBase + t * TILE_COLS + wv * 16 + r15) * D + khi;
    char* l = lds + buf * TILE_BYTES + wv * 6 * FRAG_BYTES;
#pragma unroll
    for (int ks = 0; ks < 6; ++ks) GLOAD16(g + ks * 32, l + ks * FRAG_BYTES);
  };

  stage(0, 0);
  __syncthreads();

  float s[4][4];
#pragma unroll
  for (int rs = 0; rs < 4; ++rs)
#pragma unroll
    for (int r = 0; r < 4; ++r) s[rs][r] = 0.f;

  for (int t = 0; t < NTILES; ++t) {
    if (t + 1 < NTILES) stage((t + 1) & 1, t + 1);  // prefetch overlaps compute
    const char* buf = lds + (t & 1) * TILE_BYTES;
#pragma unroll
    for (int ct = 0; ct < TILE_COLS / 16; ++ct) {
      short8 bf[6];
#pragma unroll
      for (int ks = 0; ks < 6; ++ks)
        bf[ks] = *(const short8*)(buf + (ct * 6 + ks) * FRAG_BYTES + lane * 16);
      f32x4 acc[4];
#pragma unroll
      for (int rs = 0; rs < 4; ++rs) acc[rs] = (f32x4){0.f, 0.f, 0.f, 0.f};
#pragma unroll
      for (int ks = 0; ks < 6; ++ks)
#pragma unroll
        for (int rs = 0; rs < 4; ++rs)
          acc[rs] = __builtin_amdgcn_mfma_f32_16x16x32_bf16(af[rs][ks], bf[ks], acc[rs], 0, 0, 0);
#pragma unroll
      for (int rs = 0; rs < 4; ++rs)
#pragma unroll
        for (int r = 0; r < 4; ++r)
          s[rs][r] += exp2f(fmaf(acc[rs][r], c1, c0));
    }
    __syncthreads();  // staging(t+1) complete + all waves done with buf t
  }

  // Reduce across the 16 lanes holding the 16 cols of each C tile
#pragma unroll
  for (int off = 1; off < 16; off <<= 1)
#pragma unroll
    for (int rs = 0; rs < 4; ++rs)
#pragma unroll
      for (int r = 0; r < 4; ++r) s[rs][r] += __shfl_xor(s[rs][r], off, 64);

  if (r15 == 0) {
    const int rgrp = (lane >> 4) * 4;  // C rows: (lane>>4)*4 + reg
#pragma unroll
    for (int rs = 0; rs < 4; ++rs)
#pragma unroll
      for (int r = 0; r < 4; ++r)
        partial[(size_t)chunk * N + rowBase + rs * 16 + rgrp + r] = s[rs][r];
  }
}

// ---------------- Kernel 3a: per-row LSE + per-block partial mean ----------------
__global__ __launch_bounds__(256) void finalize1_kernel(
    const float* __restrict__ partial,
    const float* __restrict__ diag,
    const float* __restrict__ wp,
    const float* __restrict__ bp,
    float* __restrict__ blocksum) {
  const float w = *wp, b = *bp;
  const float M = fabsf(w) + b;
  int i = (int)(blockIdx.x * 256 + threadIdx.x);
  float s = 0.f;
#pragma unroll
  for (int c = 0; c < NCHUNK; ++c) s += partial[(size_t)c * N + i];
  float acc = fmaf(diag[i], w, b) - (M + logf(s));
#pragma unroll
  for (int off = 32; off >= 1; off >>= 1) acc += __shfl_xor(acc, off, 64);
  __shared__ float red[4];
  if ((threadIdx.x & 63) == 0) red[threadIdx.x >> 6] = acc;
  __syncthreads();
  if (threadIdx.x == 0) blocksum[blockIdx.x] = red[0] + red[1] + red[2] + red[3];
}

// ---------------- Kernel 3b: combine 32 block sums -> loss ----------------
__global__ __launch_bounds__(64) void finalize2_kernel(
    const float* __restrict__ blocksum, float* __restrict__ out) {
  int lane = (int)threadIdx.x;
  float v = (lane < 32) ? blocksum[lane] : 0.f;
#pragma unroll
  for (int off = 32; off >= 1; off >>= 1) v += __shfl_xor(v, off, 64);
  if (lane == 0) out[0] = -v / (float)N;
}

extern "C" void kernel_launch(void* const* d_in, const int* in_sizes, int n_in,
                              void* d_out, int out_size, void* d_ws, size_t ws_size,
                              hipStream_t stream) {
  const float* x = (const float*)d_in[0];
  const float* wp = (const float*)d_in[1];
  const float* bp = (const float*)d_in[2];
  float* out = (float*)d_out;

  char* ws = (char*)d_ws;
  __hip_bfloat16* posn = (__hip_bfloat16*)ws;                 // 3,145,728 B
  __hip_bfloat16* ancn = (__hip_bfloat16*)(ws + 3145728);     // 3,145,728 B
  float* diag = (float*)(ws + 6291456);                       // 32,768 B
  float* partial = (float*)(ws + 6324224);                    // 524,288 B
  float* blocksum = (float*)(ws + 6848512);                   // 128 B

  norm_kernel<<<N / 4, 256, 0, stream>>>(x, posn, ancn, diag);
  gemm_lse_kernel<<<(N / BLOCK_ROWS) * NCHUNK, 256, 0, stream>>>(posn, ancn, wp, bp, partial);
  finalize1_kernel<<<N / 256, 256, 0, stream>>>(partial, diag, wp, bp, blocksum);
  finalize2_kernel<<<1, 64, 0, stream>>>(blocksum, out);
}

// Round 3
// 43.604 us; speedup vs baseline: 2.7437x; 1.3315x over previous
//
#include <hip/hip_runtime.h>
#include <hip/hip_bf16.h>

#define N 8192
#define D 192
#define NCHUNK 16
#define CHUNK_COLS 512
#define TILE_COLS 64
#define NTILES (CHUNK_COLS / TILE_COLS)   // 8
#define BLOCK_ROWS 256                    // 4 waves x 64 rows
#define FRAG_BYTES 1024                   // one MFMA B fragment: 64 lanes x 16B
#define TILE_BYTES ((TILE_COLS / 16) * 6 * FRAG_BYTES)  // 24576 B

typedef short short8 __attribute__((ext_vector_type(8)));
typedef float f32x4 __attribute__((ext_vector_type(4)));

#define GLOAD16(gptr, lptr)                                                               \
  __builtin_amdgcn_global_load_lds((const __attribute__((address_space(1))) void*)(gptr), \
                                   (__attribute__((address_space(3))) void*)(lptr), 16, 0, 0)

// ---------------- Kernel 1: row-normalize + diagonal dot (fp32) ----------------
// posn additionally pre-scaled by w*log2e so the GEMM accumulator directly holds
// the exp2 argument (minus the c0 offset, which seeds the accumulator).
__global__ __launch_bounds__(256) void norm_kernel(
    const float* __restrict__ x,
    const float* __restrict__ wp,
    __hip_bfloat16* __restrict__ posn,
    __hip_bfloat16* __restrict__ ancn,
    float* __restrict__ diag) {
  const float c1 = (*wp) * 1.4426950408889634f;
  int gw = (int)((blockIdx.x * 256 + threadIdx.x) >> 6);
  int lane = threadIdx.x & 63;
  if (gw >= N) return;
  const float* row = x + (size_t)gw * (2 * D);
  float p[3], a[3];
  float ssp = 0.f, ssa = 0.f, dt = 0.f;
#pragma unroll
  for (int j = 0; j < 3; ++j) {
    p[j] = row[lane + 64 * j];
    a[j] = row[D + lane + 64 * j];
    ssp += p[j] * p[j];
    ssa += a[j] * a[j];
    dt += p[j] * a[j];
  }
#pragma unroll
  for (int off = 32; off >= 1; off >>= 1) {
    ssp += __shfl_xor(ssp, off, 64);
    ssa += __shfl_xor(ssa, off, 64);
    dt += __shfl_xor(dt, off, 64);
  }
  float invp = 1.f / fmaxf(sqrtf(ssp), 1e-8f);
  float inva = 1.f / fmaxf(sqrtf(ssa), 1e-8f);
#pragma unroll
  for (int j = 0; j < 3; ++j) {
    posn[(size_t)gw * D + lane + 64 * j] = __float2bfloat16(p[j] * invp * c1);
    ancn[(size_t)gw * D + lane + 64 * j] = __float2bfloat16(a[j] * inva);
  }
  if (lane == 0) diag[gw] = dt * invp * inva;
}

// ---------------- Kernel 2: tiled GEMM + fused partial sum-exp ----------------
// Block = 4 waves x 64 rows; A (pre-scaled) in registers; B staged to LDS in
// MFMA-fragment order via global_load_lds, double-buffered.
// acc is seeded with c0 = -|w|*log2e, so sum-exp is exp2(acc) directly.
// amdgpu_waves_per_eu(2,2): grid = 2 blocks/CU, so pin the register budget at
// 256 VGPR / 2 waves per SIMD -- Round 2's compiler targeted 4 waves/EU at 128
// VGPR and spilled the 96-VGPR A-fragment array to scratch (12.8 MB WRITE_SIZE).
__global__ __launch_bounds__(256) __attribute__((amdgpu_waves_per_eu(2, 2)))
void gemm_lse_kernel(
    const __hip_bfloat16* __restrict__ posn,
    const __hip_bfloat16* __restrict__ ancn,
    const float* __restrict__ wp,
    float* __restrict__ partial) {
  __shared__ char lds[2 * TILE_BYTES];

  const int lane = (int)(threadIdx.x & 63);
  const int wv = (int)(threadIdx.x >> 6);
  const int chunk = (int)(blockIdx.x & (NCHUNK - 1));
  const int rb = (int)(blockIdx.x >> 4);
  const int rowBase = rb * BLOCK_ROWS + wv * 64;
  const int colBase = chunk * CHUNK_COLS;

  const float c0 = -fabsf(*wp) * 1.4426950408889634f;  // (b - M)*log2e, M = |w|+b

  const int r15 = lane & 15;
  const int khi = (lane >> 4) * 8;

  // A fragments: 4 rowsets x 6 ksteps, 16B/lane each (96 VGPRs, live whole kernel)
  short8 af[4][6];
#pragma unroll
  for (int rs = 0; rs < 4; ++rs)
#pragma unroll
    for (int ks = 0; ks < 6; ++ks)
      af[rs][ks] = *(const short8*)(posn + (size_t)(rowBase + rs * 16 + r15) * D + ks * 32 + khi);

  // stage tile t into buffer buf: wave wv stages coltile ct==wv (16 cols x 192 k)
  auto stage = [&](int buf, int t) {
    const __hip_bfloat16* g =
        ancn + (size_t)(colBase + t * TILE_COLS + wv * 16 + r15) * D + khi;
    char* l = lds + buf * TILE_BYTES + wv * 6 * FRAG_BYTES;
#pragma unroll
    for (int ks = 0; ks < 6; ++ks) GLOAD16(g + ks * 32, l + ks * FRAG_BYTES);
  };

  stage(0, 0);
  __syncthreads();

  float s[4][4];
#pragma unroll
  for (int rs = 0; rs < 4; ++rs)
#pragma unroll
    for (int r = 0; r < 4; ++r) s[rs][r] = 0.f;

  for (int t = 0; t < NTILES; ++t) {
    if (t + 1 < NTILES) stage((t + 1) & 1, t + 1);  // prefetch overlaps compute
    const char* buf = lds + (t & 1) * TILE_BYTES;
#pragma unroll
    for (int ct = 0; ct < TILE_COLS / 16; ++ct) {
      f32x4 acc[4];
#pragma unroll
      for (int rs = 0; rs < 4; ++rs) acc[rs] = (f32x4){c0, c0, c0, c0};
#pragma unroll
      for (int ks = 0; ks < 6; ++ks) {
        short8 bfk = *(const short8*)(buf + (ct * 6 + ks) * FRAG_BYTES + lane * 16);
#pragma unroll
        for (int rs = 0; rs < 4; ++rs)
          acc[rs] = __builtin_amdgcn_mfma_f32_16x16x32_bf16(af[rs][ks], bfk, acc[rs], 0, 0, 0);
      }
#pragma unroll
      for (int rs = 0; rs < 4; ++rs)
#pragma unroll
        for (int r = 0; r < 4; ++r)
          s[rs][r] += __builtin_amdgcn_exp2f(acc[rs][r]);
    }
    __syncthreads();  // staging(t+1) complete + all waves done with buf t
  }

  // Reduce across the 16 lanes holding the 16 cols of each C tile
#pragma unroll
  for (int off = 1; off < 16; off <<= 1)
#pragma unroll
    for (int rs = 0; rs < 4; ++rs)
#pragma unroll
      for (int r = 0; r < 4; ++r) s[rs][r] += __shfl_xor(s[rs][r], off, 64);

  if (r15 == 0) {
    const int rgrp = (lane >> 4) * 4;  // C rows: (lane>>4)*4 + reg
#pragma unroll
    for (int rs = 0; rs < 4; ++rs)
#pragma unroll
      for (int r = 0; r < 4; ++r)
        partial[(size_t)chunk * N + rowBase + rs * 16 + rgrp + r] = s[rs][r];
  }
}

// ---------------- Kernel 3a: per-row LSE + per-block partial mean ----------------
__global__ __launch_bounds__(256) void finalize1_kernel(
    const float* __restrict__ partial,
    const float* __restrict__ diag,
    const float* __restrict__ wp,
    const float* __restrict__ bp,
    float* __restrict__ blocksum) {
  const float w = *wp, b = *bp;
  const float M = fabsf(w) + b;
  int i = (int)(blockIdx.x * 256 + threadIdx.x);
  float s = 0.f;
#pragma unroll
  for (int c = 0; c < NCHUNK; ++c) s += partial[(size_t)c * N + i];
  float acc = fmaf(diag[i], w, b) - (M + logf(s));
#pragma unroll
  for (int off = 32; off >= 1; off >>= 1) acc += __shfl_xor(acc, off, 64);
  __shared__ float red[4];
  if ((threadIdx.x & 63) == 0) red[threadIdx.x >> 6] = acc;
  __syncthreads();
  if (threadIdx.x == 0) blocksum[blockIdx.x] = red[0] + red[1] + red[2] + red[3];
}

// ---------------- Kernel 3b: combine 32 block sums -> loss ----------------
__global__ __launch_bounds__(64) void finalize2_kernel(
    const float* __restrict__ blocksum, float* __restrict__ out) {
  int lane = (int)threadIdx.x;
  float v = (lane < 32) ? blocksum[lane] : 0.f;
#pragma unroll
  for (int off = 32; off >= 1; off >>= 1) v += __shfl_xor(v, off, 64);
  if (lane == 0) out[0] = -v / (float)N;
}

extern "C" void kernel_launch(void* const* d_in, const int* in_sizes, int n_in,
                              void* d_out, int out_size, void* d_ws, size_t ws_size,
                              hipStream_t stream) {
  const float* x = (const float*)d_in[0];
  const float* wp = (const float*)d_in[1];
  const float* bp = (const float*)d_in[2];
  float* out = (float*)d_out;

  char* ws = (char*)d_ws;
  __hip_bfloat16* posn = (__hip_bfloat16*)ws;                 // 3,145,728 B
  __hip_bfloat16* ancn = (__hip_bfloat16*)(ws + 3145728);     // 3,145,728 B
  float* diag = (float*)(ws + 6291456);                       // 32,768 B
  float* partial = (float*)(ws + 6324224);                    // 524,288 B
  float* blocksum = (float*)(ws + 6848512);                   // 128 B

  norm_kernel<<<N / 4, 256, 0, stream>>>(x, wp, posn, ancn, diag);
  gemm_lse_kernel<<<(N / BLOCK_ROWS) * NCHUNK, 256, 0, stream>>>(posn, ancn, wp, partial);
  finalize1_kernel<<<N / 256, 256, 0, stream>>>(partial, diag, wp, bp, blocksum);
  finalize2_kernel<<<1, 64, 0, stream>>>(blocksum, out);
}